// Round 19
// baseline (216.941 us; speedup 1.0000x reference)
//
#include <hip/hip_runtime.h>
#include <hip/hip_bf16.h>
#include <math.h>

// GMM log-prob, S=1024 D=256 K=8 d=32. Target = dtype-faithful f32 numpy ref.
// cov is replicated BIT-EXACTLY in f32 per numpy's SSE3-baseline einsum
// (mul-round + 4-lane reversed add chains + hadd tree + f32 ridge). Do not
// perturb that ordering -- it is what makes the test pass (absmax 12 < 14.88).
//
// Round 19: r17 launch geometry (2 lockstep pairs/wave, 1024 waves) + LDS-free
// P3/P4 chain. r16 post-mortem: its spill was P2's `unroll 2` writing A[c]
// (rule #20: runtime-indexed register array -> scratch), NOT register-chol
// itself (which PASSED at absmax 12.0). Fixes: P2 fully unrolled (A[c]
// static, shfl-based cov = bit-exact r15 chain); P3 register Cholesky (r16
// verbatim); P4 reads L via shfl(A[j], rr) (same bits as the LDS copy),
// x[] static, fused bf16 stores; LDS kept ONLY for X-writeback so P5b's
// b-dot stays bit-identical (ascending-j, r15 order). launch_bounds(128,1).
// Main kernel verbatim round 13..17 (MFMA, 3-way bf16 split).
// ws: L1|L2|L3 bf16 [2048*1024 ea] | b f32 [2048*32] | c f32 [2048] ~12.8 MB

typedef __attribute__((ext_vector_type(8))) short short8;
typedef __attribute__((ext_vector_type(4))) float f32x4;

__device__ __forceinline__ short f2bf(float f) {
    __hip_bfloat16 h = __float2bfloat16(f);
    return *reinterpret_cast<short*>(&h);
}
__device__ __forceinline__ float bf2f(short s) {
    __hip_bfloat16 h;
    *reinterpret_cast<short*>(&h) = s;
    return __bfloat162float(h);
}

__global__ __launch_bounds__(128, 1) void gmm_precompute(
    const float* __restrict__ mix,      // [256,8]
    const float* __restrict__ mean_p,   // [256,8,32]
    const float* __restrict__ cov_p,    // [256,8,32,32]
    const float* __restrict__ ds_stds,  // [256,32]
    short* __restrict__ L1,             // [2048,32,32] bf16 hi
    short* __restrict__ L2,             // [2048,32,32] bf16 mid
    short* __restrict__ L3,             // [2048,32,32] bf16 lo
    float* __restrict__ bOut,           // [2048,32]
    float* __restrict__ cOut)           // [2048]
{
    const int tid  = threadIdx.x;
    const int sub  = tid >> 5;                 // 0..3 half-wave in block
    const int lane = tid & 31;
    const int pair = blockIdx.x * 4 + sub;     // 0..2047
    const int dd   = pair >> 3;
    const int k    = pair & 7;

    __shared__ double Xsh[4][32][33];          // X rows only (for P5b b-dot)
    double (*X)[33] = Xsh[sub];

    // ---- P1: load W row `lane` (registers) ----
    float w[32];
    {
        const float4* wp = (const float4*)(cov_p + (size_t)pair * 1024 + lane * 32);
        #pragma unroll
        for (int q = 0; q < 8; ++q) {
            const float4 v = wp[q];
            w[4*q+0] = v.x; w[4*q+1] = v.y; w[4*q+2] = v.z; w[4*q+3] = v.w;
        }
    }

    // ---- P2: cov row in f32 (exact SSE3-emulated order) -> registers A ----
    // FULL unroll: A[c] must be statically indexed (rule #20; r16's `unroll
    // 2` here was the scratch-spill culprit).
    double A[32];
    #pragma unroll
    for (int c = 0; c < 32; ++c) {
        float p[32];
        #pragma unroll
        for (int j = 0; j < 32; ++j)
            p[j] = __fmul_rn(w[j], __shfl(w[j], c, 32));
        float acc[4];
        #pragma unroll
        for (int l = 0; l < 4; ++l) {
            float t1 = p[12+l];
            t1 = __fadd_rn(p[8+l], t1);
            t1 = __fadd_rn(p[4+l], t1);
            t1 = __fadd_rn(p[0+l], t1);
            float t2 = __fadd_rn(p[28+l], t1);
            t2 = __fadd_rn(p[24+l], t2);
            t2 = __fadd_rn(p[20+l], t2);
            acc[l] = __fadd_rn(p[16+l], t2);
        }
        float s = __fadd_rn(__fadd_rn(acc[0], acc[1]), __fadd_rn(acc[2], acc[3]));
        if (c == lane) s = __fadd_rn(s, 1.0e-5f);
        A[c] = (double)s;
    }

    // ---- P3: right-looking Cholesky (f64) in REGISTERS; lane = row. ----
    // Verbatim r16 (correctness proven there: passed absmax 12.0).
    // Element order identical to r8/r15/r17.
    double hld = 0.0, prod = 1.0, myinv = 0.0;
    #pragma unroll
    for (int c = 0; c < 32; ++c) {
        const double dv  = __shfl(A[c], c, 32);    // C[c][c] fully updated
        const double dcc = sqrt(dv);
        prod *= dv;
        if ((c & 7) == 7) { hld += log(prod); prod = 1.0; }
        const double invd = 1.0 / dcc;
        if (lane == c) myinv = invd;
        const double lrc = A[c] * invd;
        A[c] = (lane == c) ? dcc : lrc;            // lanes r<c keep garbage (unused)
        #pragma unroll
        for (int c2 = c + 1; c2 < 32; ++c2) {
            const double lc2c = __shfl(A[c], c2, 32);   // L[c2][c]
            A[c2] = (lane > c) ? fma(-A[c], lc2c, A[c2]) : A[c2];
        }
    }
    hld *= 0.5;   // dv = Lcc^2

    // ---- P4 (+fused P5a): forward substitution, lane = column. ----
    // L[rr][j] = shfl(A[j], rr) -- identical bits to the old LDS copy.
    // x[] lane-local, ALL statically indexed; bf16 split + stores inline.
    // FP sequence identical to r15/r17.
    double x[32];
    #pragma unroll
    for (int rr = 0; rr < 32; ++rr) {
        double s = (rr == lane) ? 1.0 : 0.0;
        #pragma unroll
        for (int j = 0; j < rr; ++j) {
            const double Lrj = __shfl(A[j], rr, 32);   // L[rr][j], uniform idx
            s = fma(-Lrj, x[j], s);
        }
        const double xr = s * __shfl(myinv, rr, 32);   // * 1/L[rr][rr]
        x[rr] = xr;
        X[rr][lane] = xr;                   // X row rr (for P5b only)

        const float f0 = (float)xr;
        const short h1 = f2bf(f0);
        const float r1 = f0 - bf2f(h1);
        const short h2 = f2bf(r1);
        const float r2 = r1 - bf2f(h2);
        const short h3 = f2bf(r2);
        const size_t base = (size_t)pair * 1024 + (size_t)rr * 32 + lane;
        L1[base] = h1; L2[base] = h2; L3[base] = h3;
    }

    // ---- P5b: b row `lane` = sum_j X[lane][j] * mu[j] (f64, asc j) ----
    const double mu_l = (double)mean_p[(size_t)pair * 32 + lane];
    double bacc = 0.0;
    #pragma unroll 4
    for (int j = 0; j < 32; ++j)
        bacc += X[lane][j] * __shfl(mu_l, j, 32);
    bOut[(size_t)pair * 32 + lane] = (float)bacc;

    // ---- P5c: c constant (product-butterfly for sum log std, 1 log) ----
    double sprod = (double)ds_stds[dd * 32 + lane];
    #pragma unroll
    for (int off = 16; off >= 1; off >>= 1)
        sprod *= __shfl_xor(sprod, off, 32);
    if (lane == 0) {
        const double lsd = log(sprod);
        const float* mrow = mix + dd * 8;
        double mx = (double)mrow[0];
        #pragma unroll
        for (int q = 1; q < 8; ++q) mx = fmax(mx, (double)mrow[q]);
        double se = 0.0;
        #pragma unroll
        for (int q = 0; q < 8; ++q) se += exp((double)mrow[q] - mx);
        const double logpi = (double)mrow[k] - mx - log(se);
        const double LOG2PI = 1.8378770664093454836;  // log(2*pi)
        cOut[pair] = (float)(logpi - hld - 16.0 * LOG2PI - lsd);
    }
}

// MFMA heavy kernel: verbatim round 13..17 (passing).
__global__ __launch_bounds__(64) void gmm_main(
    const float* __restrict__ data,     // [1024,256,32]
    const float* __restrict__ ds_means, // [256,32]
    const float* __restrict__ ds_stds,  // [256,32]
    const short* __restrict__ L1,       // [2048,32,32] bf16 hi
    const short* __restrict__ L2,       // mid
    const short* __restrict__ L3,       // lo
    const float* __restrict__ bvec,     // [2048,32]
    const float* __restrict__ cdk,      // [2048]
    float* __restrict__ out)            // [1024,256]
{
    const int dd = blockIdx.x;          // 0..255
    const int sc = blockIdx.y;          // 0..15
    const int t  = threadIdx.x;         // 0..63

    __shared__ short y1[4][64][8];      // [j-block][sample][j-in-block]
    __shared__ short y2[4][64][8];
    __shared__ short y3[4][64][8];

    float mn[32], is[32];
    {
        const float4* mp = (const float4*)(ds_means + dd * 32);
        const float4* sp = (const float4*)(ds_stds + dd * 32);
        #pragma unroll
        for (int q = 0; q < 8; ++q) {
            const float4 mv = mp[q];
            const float4 sv = sp[q];
            const int j4 = 4 * q;
            mn[j4+0] = mv.x; mn[j4+1] = mv.y; mn[j4+2] = mv.z; mn[j4+3] = mv.w;
            is[j4+0] = 1.0f / sv.x; is[j4+1] = 1.0f / sv.y;
            is[j4+2] = 1.0f / sv.z; is[j4+3] = 1.0f / sv.w;
        }
    }

    {
        const int s = sc * 64 + t;
        const float4* xp = (const float4*)(data + ((size_t)s * 256 + dd) * 32);
        float y[32];
        #pragma unroll
        for (int q = 0; q < 8; ++q) {
            const float4 v = xp[q];
            const int j4 = 4 * q;
            y[j4+0] = (v.x - mn[j4+0]) * is[j4+0];
            y[j4+1] = (v.y - mn[j4+1]) * is[j4+1];
            y[j4+2] = (v.z - mn[j4+2]) * is[j4+2];
            y[j4+3] = (v.w - mn[j4+3]) * is[j4+3];
        }
        #pragma unroll
        for (int jb = 0; jb < 4; ++jb) {
            short8 v1, v2, v3;
            #pragma unroll
            for (int e = 0; e < 8; ++e) {
                const float f0 = y[jb*8 + e];
                const short h1 = f2bf(f0);
                const float r1 = f0 - bf2f(h1);
                const short h2 = f2bf(r1);
                const float r2 = r1 - bf2f(h2);
                v1[e] = h1; v2[e] = h2; v3[e] = f2bf(r2);
            }
            *(short8*)&y1[jb][t][0] = v1;
            *(short8*)&y2[jb][t][0] = v2;
            *(short8*)&y3[jb][t][0] = v3;
        }
    }
    __syncthreads();

    const int scol = t & 15;            // sample col / A row within tile
    const int g    = t >> 4;            // k-group (j-block) 0..3

    short8 vb1[4], vb2[4], vb3[4];
    #pragma unroll
    for (int st = 0; st < 4; ++st) {
        const int sl = st * 16 + scol;
        vb1[st] = *(const short8*)&y1[g][sl][0];
        vb2[st] = *(const short8*)&y2[g][sl][0];
        vb3[st] = *(const short8*)&y3[g][sl][0];
    }

    float maha[4][8];
    #pragma unroll
    for (int st = 0; st < 4; ++st)
        #pragma unroll
        for (int k = 0; k < 8; ++k) maha[st][k] = 0.0f;

    #pragma unroll
    for (int mt = 0; mt < 16; ++mt) {
        const int k  = mt >> 1;
        const int ib = (mt & 1) * 16;
        const size_t abase = ((size_t)(dd * 8 + k)) * 1024
                           + (size_t)(ib + scol) * 32 + g * 8;
        const short8 a1 = *(const short8*)(L1 + abase);
        const short8 a2 = *(const short8*)(L2 + abase);
        const short8 a3 = *(const short8*)(L3 + abase);
        const float4 bq = *(const float4*)(bvec + (dd * 8 + k) * 32 + ib + g * 4);
        f32x4 cinit;
        cinit[0] = -bq.x; cinit[1] = -bq.y; cinit[2] = -bq.z; cinit[3] = -bq.w;

        f32x4 acc[4];
        #pragma unroll
        for (int st = 0; st < 4; ++st) acc[st] = cinit;

        #pragma unroll
        for (int st = 0; st < 4; ++st) {
            acc[st] = __builtin_amdgcn_mfma_f32_16x16x32_bf16(a1, vb1[st], acc[st], 0, 0, 0);
            acc[st] = __builtin_amdgcn_mfma_f32_16x16x32_bf16(a1, vb2[st], acc[st], 0, 0, 0);
            acc[st] = __builtin_amdgcn_mfma_f32_16x16x32_bf16(a2, vb1[st], acc[st], 0, 0, 0);
            acc[st] = __builtin_amdgcn_mfma_f32_16x16x32_bf16(a2, vb2[st], acc[st], 0, 0, 0);
            acc[st] = __builtin_amdgcn_mfma_f32_16x16x32_bf16(a1, vb3[st], acc[st], 0, 0, 0);
            acc[st] = __builtin_amdgcn_mfma_f32_16x16x32_bf16(a3, vb1[st], acc[st], 0, 0, 0);
        }

        #pragma unroll
        for (int st = 0; st < 4; ++st) {
            float sq = fmaf(acc[st][0], acc[st][0],
                       fmaf(acc[st][1], acc[st][1],
                       fmaf(acc[st][2], acc[st][2], acc[st][3] * acc[st][3])));
            sq += __shfl_xor(sq, 16);
            sq += __shfl_xor(sq, 32);
            maha[st][k] += sq;
        }
    }

    const float* cb = cdk + dd * 8;
    #pragma unroll
    for (int st = 0; st < 4; ++st) {
        float a[8];
        #pragma unroll
        for (int k = 0; k < 8; ++k) a[k] = cb[k] - 0.5f * maha[st][k];
        float m = a[0];
        #pragma unroll
        for (int k = 1; k < 8; ++k) m = fmaxf(m, a[k]);
        float e = 0.0f;
        #pragma unroll
        for (int k = 0; k < 8; ++k) e += expf(a[k] - m);
        if (t < 16) {
            const int s = sc * 64 + st * 16 + scol;
            out[(size_t)s * 256 + dd] = m + logf(e);
        }
    }
}

extern "C" void kernel_launch(void* const* d_in, const int* in_sizes, int n_in,
                              void* d_out, int out_size, void* d_ws, size_t ws_size,
                              hipStream_t stream) {
    const float* data   = (const float*)d_in[0];   // [1024,256,32]
    const float* mix    = (const float*)d_in[1];   // [256,8]
    const float* mean_p = (const float*)d_in[2];   // [256,8,32]
    const float* cov_p  = (const float*)d_in[3];   // [256,8,32,32]
    const float* ds_m   = (const float*)d_in[4];   // [256,32]
    const float* ds_s   = (const float*)d_in[5];   // [256,32]
    float* out = (float*)d_out;

    short* L1 = (short*)d_ws;                   // 2048*1024 bf16
    short* L2 = L1 + 2048 * 1024;
    short* L3 = L2 + 2048 * 1024;
    float* bvec = (float*)(L3 + 2048 * 1024);   // 2048*32 f32
    float* cdk  = bvec + 2048 * 32;             // 2048 f32

    gmm_precompute<<<512, 128, 0, stream>>>(mix, mean_p, cov_p, ds_s,
                                            L1, L2, L3, bvec, cdk);
    dim3 grid(256, 16);
    gmm_main<<<grid, 64, 0, stream>>>(data, ds_m, ds_s, L1, L2, L3,
                                      bvec, cdk, out);
}

// Round 20
// 125.091 us; speedup vs baseline: 1.7343x; 1.7343x over previous
//
#include <hip/hip_runtime.h>
#include <hip/hip_bf16.h>
#include <math.h>

// GMM log-prob, S=1024 D=256 K=8 d=32. Target = dtype-faithful f32 numpy ref.
// cov is replicated BIT-EXACTLY in f32 per numpy's SSE3-baseline einsum
// (mul-round + 4-lane reversed add chains + hadd tree + f32 ridge). Do not
// perturb that ordering -- it is what makes the test pass (absmax 12 < 14.88).
//
// Round 20: register-interleaved dual-chain precompute. Diagnosis: at
// 1 wave/SIMD the kernel is dependent-latency bound (VALUBusy 14%); r17's
// 2-pairs-per-wave is lockstep (no mutual hiding); r18's 2-wave attempt
// regressed. Here each WAVE carries TWO chains (pairs A,B) in separate
// registers, instructions interleaved at compile time -> chain A's bubbles
// filled by chain B. All lanes compute both chains (upper half duplicates);
// stores guarded to lane<32; LDS dup-writes are same-value (benign).
// Per-chain FP sequences verbatim r17 -> bit-identical outputs.
// Main kernel verbatim round 13..17 (MFMA, 3-way bf16 split).
// ws: L1|L2|L3 bf16 [2048*1024 ea] | b f32 [2048*32] | c f32 [2048] ~12.8 MB

typedef __attribute__((ext_vector_type(8))) short short8;
typedef __attribute__((ext_vector_type(4))) float f32x4;

__device__ __forceinline__ short f2bf(float f) {
    __hip_bfloat16 h = __float2bfloat16(f);
    return *reinterpret_cast<short*>(&h);
}
__device__ __forceinline__ float bf2f(short s) {
    __hip_bfloat16 h;
    *reinterpret_cast<short*>(&h) = s;
    return __bfloat162float(h);
}

__global__ __launch_bounds__(128, 1) void gmm_precompute(
    const float* __restrict__ mix,      // [256,8]
    const float* __restrict__ mean_p,   // [256,8,32]
    const float* __restrict__ cov_p,    // [256,8,32,32]
    const float* __restrict__ ds_stds,  // [256,32]
    short* __restrict__ L1,             // [2048,32,32] bf16 hi
    short* __restrict__ L2,             // [2048,32,32] bf16 mid
    short* __restrict__ L3,             // [2048,32,32] bf16 lo
    float* __restrict__ bOut,           // [2048,32]
    float* __restrict__ cOut)           // [2048]
{
    const int tid   = threadIdx.x;
    const int wv    = tid >> 6;                // wave in block: 0..1
    const int lane  = tid & 63;
    const int r     = lane & 31;
    const bool lo32 = (lane < 32);
    const int pairA = blockIdx.x * 4 + wv * 2; // 0..2047
    const int pairB = pairA + 1;
    const int ddA   = pairA >> 3, kA = pairA & 7;
    const int ddB   = pairB >> 3, kB = pairB & 7;

    __shared__ double Csh[4][32][33];          // [2 waves][2 chains]
    double (*CA)[33] = Csh[wv * 2 + 0];
    double (*CB)[33] = Csh[wv * 2 + 1];

    // ---- P1: load W row r for both chains (all lanes) ----
    float wA[32], wB[32];
    {
        const float4* wpA = (const float4*)(cov_p + (size_t)pairA * 1024 + r * 32);
        const float4* wpB = (const float4*)(cov_p + (size_t)pairB * 1024 + r * 32);
        #pragma unroll
        for (int q = 0; q < 8; ++q) {
            const float4 vA = wpA[q];
            const float4 vB = wpB[q];
            wA[4*q+0] = vA.x; wA[4*q+1] = vA.y; wA[4*q+2] = vA.z; wA[4*q+3] = vA.w;
            wB[4*q+0] = vB.x; wB[4*q+1] = vB.y; wB[4*q+2] = vB.z; wB[4*q+3] = vB.w;
        }
    }

    // ---- P2: cov rows in f32 (exact SSE3-emulated order) -> LDS f64 ----
    // Two independent chains interleaved; FP order per chain = r17.
    #pragma unroll 2
    for (int c = 0; c < 32; ++c) {
        float pA[32], pB[32];
        #pragma unroll
        for (int j = 0; j < 32; ++j) {
            pA[j] = __fmul_rn(wA[j], __shfl(wA[j], c, 32));
            pB[j] = __fmul_rn(wB[j], __shfl(wB[j], c, 32));
        }
        float aA[4], aB[4];
        #pragma unroll
        for (int l = 0; l < 4; ++l) {
            float t1A = pA[12+l], t1B = pB[12+l];
            t1A = __fadd_rn(pA[8+l], t1A);  t1B = __fadd_rn(pB[8+l], t1B);
            t1A = __fadd_rn(pA[4+l], t1A);  t1B = __fadd_rn(pB[4+l], t1B);
            t1A = __fadd_rn(pA[0+l], t1A);  t1B = __fadd_rn(pB[0+l], t1B);
            float t2A = __fadd_rn(pA[28+l], t1A);
            float t2B = __fadd_rn(pB[28+l], t1B);
            t2A = __fadd_rn(pA[24+l], t2A); t2B = __fadd_rn(pB[24+l], t2B);
            t2A = __fadd_rn(pA[20+l], t2A); t2B = __fadd_rn(pB[20+l], t2B);
            aA[l] = __fadd_rn(pA[16+l], t2A);
            aB[l] = __fadd_rn(pB[16+l], t2B);
        }
        float sA = __fadd_rn(__fadd_rn(aA[0], aA[1]), __fadd_rn(aA[2], aA[3]));
        float sB = __fadd_rn(__fadd_rn(aB[0], aB[1]), __fadd_rn(aB[2], aB[3]));
        if (c == r) { sA = __fadd_rn(sA, 1.0e-5f); sB = __fadd_rn(sB, 1.0e-5f); }
        if (lo32) { CA[r][c] = (double)sA; CB[r][c] = (double)sB; }
    }

    // ---- P3: blocked Cholesky (f64), 4-col panels; dual chain ----
    // Element-wise FP order per chain identical to r15/r17.
    double hldA = 0.0, prodA = 1.0, hldB = 0.0, prodB = 1.0;
    double cregA[4], lregA[4], cregB[4], lregB[4];
    #pragma unroll
    for (int q = 0; q < 4; ++q) { cregA[q] = CA[r][q]; cregB[q] = CB[r][q]; }

    #pragma unroll
    for (int cb = 0; cb < 8; ++cb) {
        const int c0 = cb * 4;
        #pragma unroll
        for (int q = 0; q < 4; ++q) {
            const int c = c0 + q;
            #pragma unroll
            for (int q2 = 0; q2 < 4; ++q2) {
                if (q2 < q) {
                    const double ljcA = __shfl(lregA[q2], c, 32);
                    const double ljcB = __shfl(lregB[q2], c, 32);
                    cregA[q] = fma(-lregA[q2], ljcA, cregA[q]);
                    cregB[q] = fma(-lregB[q2], ljcB, cregB[q]);
                }
            }
            const double dvA  = __shfl(cregA[q], c, 32);
            const double dvB  = __shfl(cregB[q], c, 32);
            const double dccA = sqrt(dvA);
            const double dccB = sqrt(dvB);
            prodA *= dvA; prodB *= dvB;
            if ((c & 7) == 7) {
                hldA += log(prodA); prodA = 1.0;
                hldB += log(prodB); prodB = 1.0;
            }
            const double invdA = 1.0 / dccA;
            const double invdB = 1.0 / dccB;
            lregA[q] = (r == c) ? dccA : cregA[q] * invdA;
            lregB[q] = (r == c) ? dccB : cregB[q] * invdB;
            if (lane == c) { CA[c][32] = invdA; CB[c][32] = invdB; }
        }
        if (lo32) {
            #pragma unroll
            for (int q = 0; q < 4; ++q) {
                CA[r][c0 + q] = lregA[q];
                CB[r][c0 + q] = lregB[q];
            }
        }
        if (cb < 7) {
            #pragma unroll
            for (int q = 0; q < 4; ++q) {
                const int c2 = c0 + 4 + q;
                double tA = CA[r][c2], tB = CB[r][c2];
                #pragma unroll
                for (int q2 = 0; q2 < 4; ++q2) {
                    const double lA = __shfl(lregA[q2], c2, 32);
                    const double lB = __shfl(lregB[q2], c2, 32);
                    tA = fma(-lregA[q2], lA, tA);
                    tB = fma(-lregB[q2], lB, tB);
                }
                cregA[q] = tA; cregB[q] = tB;
            }
            #pragma unroll
            for (int c2 = 0; c2 < 32; ++c2) {
                if (c2 >= c0 + 8) {
                    double tA = CA[r][c2], tB = CB[r][c2];
                    #pragma unroll
                    for (int q2 = 0; q2 < 4; ++q2) {
                        const double lA = __shfl(lregA[q2], c2, 32);
                        const double lB = __shfl(lregB[q2], c2, 32);
                        tA = fma(-lregA[q2], lA, tA);
                        tB = fma(-lregB[q2], lB, tB);
                    }
                    if (lo32) { CA[r][c2] = tA; CB[r][c2] = tB; }
                }
            }
        }
    }
    hldA *= 0.5; hldB *= 0.5;

    // ---- P4 (+fused P5a): forward substitution, r = column; dual chain ----
    // x[] static-indexed regs (rule #20); bf16 split + stores inline.
    double xA[32], xB[32];
    #pragma unroll
    for (int rr = 0; rr < 32; ++rr) {
        double sA = (rr == r) ? 1.0 : 0.0;
        double sB = sA;
        #pragma unroll
        for (int j = 0; j < rr; ++j) {
            sA = fma(-CA[rr][j], xA[j], sA);
            sB = fma(-CB[rr][j], xB[j], sB);
        }
        const double xrA = sA * CA[rr][32];
        const double xrB = sB * CB[rr][32];
        xA[rr] = xrA; xB[rr] = xrB;

        const float f0A = (float)xrA;
        const float f0B = (float)xrB;
        const short h1A = f2bf(f0A), h1B = f2bf(f0B);
        const float r1A = f0A - bf2f(h1A), r1B = f0B - bf2f(h1B);
        const short h2A = f2bf(r1A), h2B = f2bf(r1B);
        const float r2A = r1A - bf2f(h2A), r2B = r1B - bf2f(h2B);
        const short h3A = f2bf(r2A), h3B = f2bf(r2B);
        if (lo32) {
            CA[rr][r] = xrA;               // X row rr (L row rr is dead)
            CB[rr][r] = xrB;
            const size_t bA = (size_t)pairA * 1024 + (size_t)rr * 32 + r;
            const size_t bB = (size_t)pairB * 1024 + (size_t)rr * 32 + r;
            L1[bA] = h1A; L2[bA] = h2A; L3[bA] = h3A;
            L1[bB] = h1B; L2[bB] = h2B; L3[bB] = h3B;
        }
    }

    // ---- P5b: b rows (f64, asc j); dual chain ----
    const double muA = (double)mean_p[(size_t)pairA * 32 + r];
    const double muB = (double)mean_p[(size_t)pairB * 32 + r];
    double baccA = 0.0, baccB = 0.0;
    #pragma unroll 4
    for (int j = 0; j < 32; ++j) {
        baccA += CA[r][j] * __shfl(muA, j, 32);
        baccB += CB[r][j] * __shfl(muB, j, 32);
    }
    if (lo32) {
        bOut[(size_t)pairA * 32 + r] = (float)baccA;
        bOut[(size_t)pairB * 32 + r] = (float)baccB;
    }

    // ---- P5c: c constants (product-butterfly, 1 log); dual chain ----
    double spA = (double)ds_stds[ddA * 32 + r];
    double spB = (double)ds_stds[ddB * 32 + r];
    #pragma unroll
    for (int off = 16; off >= 1; off >>= 1) {
        spA *= __shfl_xor(spA, off, 32);
        spB *= __shfl_xor(spB, off, 32);
    }
    if (lane == 0) {
        const double LOG2PI = 1.8378770664093454836;
        {
            const double lsd = log(spA);
            const float* mrow = mix + ddA * 8;
            double mx = (double)mrow[0];
            #pragma unroll
            for (int q = 1; q < 8; ++q) mx = fmax(mx, (double)mrow[q]);
            double se = 0.0;
            #pragma unroll
            for (int q = 0; q < 8; ++q) se += exp((double)mrow[q] - mx);
            const double logpi = (double)mrow[kA] - mx - log(se);
            cOut[pairA] = (float)(logpi - hldA - 16.0 * LOG2PI - lsd);
        }
        {
            const double lsd = log(spB);
            const float* mrow = mix + ddB * 8;
            double mx = (double)mrow[0];
            #pragma unroll
            for (int q = 1; q < 8; ++q) mx = fmax(mx, (double)mrow[q]);
            double se = 0.0;
            #pragma unroll
            for (int q = 0; q < 8; ++q) se += exp((double)mrow[q] - mx);
            const double logpi = (double)mrow[kB] - mx - log(se);
            cOut[pairB] = (float)(logpi - hldB - 16.0 * LOG2PI - lsd);
        }
    }
}

// MFMA heavy kernel: verbatim round 13..17 (passing).
__global__ __launch_bounds__(64) void gmm_main(
    const float* __restrict__ data,     // [1024,256,32]
    const float* __restrict__ ds_means, // [256,32]
    const float* __restrict__ ds_stds,  // [256,32]
    const short* __restrict__ L1,       // [2048,32,32] bf16 hi
    const short* __restrict__ L2,       // mid
    const short* __restrict__ L3,       // lo
    const float* __restrict__ bvec,     // [2048,32]
    const float* __restrict__ cdk,      // [2048]
    float* __restrict__ out)            // [1024,256]
{
    const int dd = blockIdx.x;          // 0..255
    const int sc = blockIdx.y;          // 0..15
    const int t  = threadIdx.x;         // 0..63

    __shared__ short y1[4][64][8];      // [j-block][sample][j-in-block]
    __shared__ short y2[4][64][8];
    __shared__ short y3[4][64][8];

    float mn[32], is[32];
    {
        const float4* mp = (const float4*)(ds_means + dd * 32);
        const float4* sp = (const float4*)(ds_stds + dd * 32);
        #pragma unroll
        for (int q = 0; q < 8; ++q) {
            const float4 mv = mp[q];
            const float4 sv = sp[q];
            const int j4 = 4 * q;
            mn[j4+0] = mv.x; mn[j4+1] = mv.y; mn[j4+2] = mv.z; mn[j4+3] = mv.w;
            is[j4+0] = 1.0f / sv.x; is[j4+1] = 1.0f / sv.y;
            is[j4+2] = 1.0f / sv.z; is[j4+3] = 1.0f / sv.w;
        }
    }

    {
        const int s = sc * 64 + t;
        const float4* xp = (const float4*)(data + ((size_t)s * 256 + dd) * 32);
        float y[32];
        #pragma unroll
        for (int q = 0; q < 8; ++q) {
            const float4 v = xp[q];
            const int j4 = 4 * q;
            y[j4+0] = (v.x - mn[j4+0]) * is[j4+0];
            y[j4+1] = (v.y - mn[j4+1]) * is[j4+1];
            y[j4+2] = (v.z - mn[j4+2]) * is[j4+2];
            y[j4+3] = (v.w - mn[j4+3]) * is[j4+3];
        }
        #pragma unroll
        for (int jb = 0; jb < 4; ++jb) {
            short8 v1, v2, v3;
            #pragma unroll
            for (int e = 0; e < 8; ++e) {
                const float f0 = y[jb*8 + e];
                const short h1 = f2bf(f0);
                const float r1 = f0 - bf2f(h1);
                const short h2 = f2bf(r1);
                const float r2 = r1 - bf2f(h2);
                v1[e] = h1; v2[e] = h2; v3[e] = f2bf(r2);
            }
            *(short8*)&y1[jb][t][0] = v1;
            *(short8*)&y2[jb][t][0] = v2;
            *(short8*)&y3[jb][t][0] = v3;
        }
    }
    __syncthreads();

    const int scol = t & 15;            // sample col / A row within tile
    const int g    = t >> 4;            // k-group (j-block) 0..3

    short8 vb1[4], vb2[4], vb3[4];
    #pragma unroll
    for (int st = 0; st < 4; ++st) {
        const int sl = st * 16 + scol;
        vb1[st] = *(const short8*)&y1[g][sl][0];
        vb2[st] = *(const short8*)&y2[g][sl][0];
        vb3[st] = *(const short8*)&y3[g][sl][0];
    }

    float maha[4][8];
    #pragma unroll
    for (int st = 0; st < 4; ++st)
        #pragma unroll
        for (int k = 0; k < 8; ++k) maha[st][k] = 0.0f;

    #pragma unroll
    for (int mt = 0; mt < 16; ++mt) {
        const int k  = mt >> 1;
        const int ib = (mt & 1) * 16;
        const size_t abase = ((size_t)(dd * 8 + k)) * 1024
                           + (size_t)(ib + scol) * 32 + g * 8;
        const short8 a1 = *(const short8*)(L1 + abase);
        const short8 a2 = *(const short8*)(L2 + abase);
        const short8 a3 = *(const short8*)(L3 + abase);
        const float4 bq = *(const float4*)(bvec + (dd * 8 + k) * 32 + ib + g * 4);
        f32x4 cinit;
        cinit[0] = -bq.x; cinit[1] = -bq.y; cinit[2] = -bq.z; cinit[3] = -bq.w;

        f32x4 acc[4];
        #pragma unroll
        for (int st = 0; st < 4; ++st) acc[st] = cinit;

        #pragma unroll
        for (int st = 0; st < 4; ++st) {
            acc[st] = __builtin_amdgcn_mfma_f32_16x16x32_bf16(a1, vb1[st], acc[st], 0, 0, 0);
            acc[st] = __builtin_amdgcn_mfma_f32_16x16x32_bf16(a1, vb2[st], acc[st], 0, 0, 0);
            acc[st] = __builtin_amdgcn_mfma_f32_16x16x32_bf16(a2, vb1[st], acc[st], 0, 0, 0);
            acc[st] = __builtin_amdgcn_mfma_f32_16x16x32_bf16(a2, vb2[st], acc[st], 0, 0, 0);
            acc[st] = __builtin_amdgcn_mfma_f32_16x16x32_bf16(a1, vb3[st], acc[st], 0, 0, 0);
            acc[st] = __builtin_amdgcn_mfma_f32_16x16x32_bf16(a3, vb1[st], acc[st], 0, 0, 0);
        }

        #pragma unroll
        for (int st = 0; st < 4; ++st) {
            float sq = fmaf(acc[st][0], acc[st][0],
                       fmaf(acc[st][1], acc[st][1],
                       fmaf(acc[st][2], acc[st][2], acc[st][3] * acc[st][3])));
            sq += __shfl_xor(sq, 16);
            sq += __shfl_xor(sq, 32);
            maha[st][k] += sq;
        }
    }

    const float* cb = cdk + dd * 8;
    #pragma unroll
    for (int st = 0; st < 4; ++st) {
        float a[8];
        #pragma unroll
        for (int k = 0; k < 8; ++k) a[k] = cb[k] - 0.5f * maha[st][k];
        float m = a[0];
        #pragma unroll
        for (int k = 1; k < 8; ++k) m = fmaxf(m, a[k]);
        float e = 0.0f;
        #pragma unroll
        for (int k = 0; k < 8; ++k) e += expf(a[k] - m);
        if (t < 16) {
            const int s = sc * 64 + st * 16 + scol;
            out[(size_t)s * 256 + dd] = m + logf(e);
        }
    }
}

extern "C" void kernel_launch(void* const* d_in, const int* in_sizes, int n_in,
                              void* d_out, int out_size, void* d_ws, size_t ws_size,
                              hipStream_t stream) {
    const float* data   = (const float*)d_in[0];   // [1024,256,32]
    const float* mix    = (const float*)d_in[1];   // [256,8]
    const float* mean_p = (const float*)d_in[2];   // [256,8,32]
    const float* cov_p  = (const float*)d_in[3];   // [256,8,32,32]
    const float* ds_m   = (const float*)d_in[4];   // [256,32]
    const float* ds_s   = (const float*)d_in[5];   // [256,32]
    float* out = (float*)d_out;

    short* L1 = (short*)d_ws;                   // 2048*1024 bf16
    short* L2 = L1 + 2048 * 1024;
    short* L3 = L2 + 2048 * 1024;
    float* bvec = (float*)(L3 + 2048 * 1024);   // 2048*32 f32
    float* cdk  = bvec + 2048 * 32;             // 2048 f32

    gmm_precompute<<<512, 128, 0, stream>>>(mix, mean_p, cov_p, ds_s,
                                            L1, L2, L3, bvec, cdk);
    dim3 grid(256, 16);
    gmm_main<<<grid, 64, 0, stream>>>(data, ds_m, ds_s, L1, L2, L3,
                                      bvec, cdk, out);
}

// Round 21
// 86.559 us; speedup vs baseline: 2.5063x; 1.4452x over previous
//
#include <hip/hip_runtime.h>
#include <hip/hip_bf16.h>
#include <math.h>

// GMM log-prob, S=1024 D=256 K=8 d=32. Target = dtype-faithful f32 numpy ref.
// cov is replicated BIT-EXACTLY in f32 per numpy's SSE3-baseline einsum
// (mul-round + 4-lane reversed add chains + hadd tree + f32 ridge). Do not
// perturb that ordering -- it is what makes the test pass (absmax 12 < 14.88).
//
// Round 21 = verbatim r17 (best: 86.7us) with ONE change: P2's c-loop and
// P5b's j-loop are FULLY unrolled so every __shfl index is compile-time
// -> lowers to v_readlane_b32 (VALU) instead of ds_bpermute (LDS pipe +
// lgkmcnt round trip). r20's post-mortem: stalls scale with op count, and
// P2's 1024 runtime-index bpermutes are the prime suspect for the ~105k
// stall cycles at 1 wave/SIMD. Values and FP order are bit-identical.
// Main kernel verbatim round 13..17 (MFMA, 3-way bf16 split).
// ws: L1|L2|L3 bf16 [2048*1024 ea] | b f32 [2048*32] | c f32 [2048] ~12.8 MB

typedef __attribute__((ext_vector_type(8))) short short8;
typedef __attribute__((ext_vector_type(4))) float f32x4;

__device__ __forceinline__ short f2bf(float f) {
    __hip_bfloat16 h = __float2bfloat16(f);
    return *reinterpret_cast<short*>(&h);
}
__device__ __forceinline__ float bf2f(short s) {
    __hip_bfloat16 h;
    *reinterpret_cast<short*>(&h) = s;
    return __bfloat162float(h);
}

__global__ __launch_bounds__(128, 1) void gmm_precompute(
    const float* __restrict__ mix,      // [256,8]
    const float* __restrict__ mean_p,   // [256,8,32]
    const float* __restrict__ cov_p,    // [256,8,32,32]
    const float* __restrict__ ds_stds,  // [256,32]
    short* __restrict__ L1,             // [2048,32,32] bf16 hi
    short* __restrict__ L2,             // [2048,32,32] bf16 mid
    short* __restrict__ L3,             // [2048,32,32] bf16 lo
    float* __restrict__ bOut,           // [2048,32]
    float* __restrict__ cOut)           // [2048]
{
    const int tid  = threadIdx.x;
    const int sub  = tid >> 5;                 // 0..3 half-wave in block
    const int lane = tid & 31;
    const int pair = blockIdx.x * 4 + sub;     // 0..2047
    const int dd   = pair >> 3;
    const int k    = pair & 7;

    __shared__ double Csh[4][32][33];          // [sub][row][col]; col32 = invD
    double (*C)[33] = Csh[sub];

    // ---- P1: load W row `lane` (registers) ----
    float w[32];
    {
        const float4* wp = (const float4*)(cov_p + (size_t)pair * 1024 + lane * 32);
        #pragma unroll
        for (int q = 0; q < 8; ++q) {
            const float4 v = wp[q];
            w[4*q+0] = v.x; w[4*q+1] = v.y; w[4*q+2] = v.z; w[4*q+3] = v.w;
        }
    }

    // ---- P2: cov row in f32 (exact SSE3-emulated order) -> LDS f64 ----
    // FULL unroll: c is compile-time -> __shfl lowers to v_readlane (no LDS
    // pipe, no lgkmcnt). FP chain identical to r15/r17.
    #pragma unroll
    for (int c = 0; c < 32; ++c) {
        float p[32];
        #pragma unroll
        for (int j = 0; j < 32; ++j)
            p[j] = __fmul_rn(w[j], __shfl(w[j], c, 32));
        float acc[4];
        #pragma unroll
        for (int l = 0; l < 4; ++l) {
            float t1 = p[12+l];
            t1 = __fadd_rn(p[8+l], t1);
            t1 = __fadd_rn(p[4+l], t1);
            t1 = __fadd_rn(p[0+l], t1);
            float t2 = __fadd_rn(p[28+l], t1);
            t2 = __fadd_rn(p[24+l], t2);
            t2 = __fadd_rn(p[20+l], t2);
            acc[l] = __fadd_rn(p[16+l], t2);
        }
        float s = __fadd_rn(__fadd_rn(acc[0], acc[1]), __fadd_rn(acc[2], acc[3]));
        if (c == lane) s = __fadd_rn(s, 1.0e-5f);
        C[lane][c] = (double)s;
    }

    // ---- P3: blocked Cholesky (f64), 4-col panels, lane = row. ----
    // Element-wise FP order identical to the unblocked version. All shuffle
    // indices already compile-time (cb/q loops fully unrolled).
    double hld = 0.0, prod = 1.0;
    double creg[4], lreg[4];
    #pragma unroll
    for (int q = 0; q < 4; ++q) creg[q] = C[lane][q];

    #pragma unroll
    for (int cb = 0; cb < 8; ++cb) {
        const int c0 = cb * 4;
        // panel: finalize columns c0..c0+3
        #pragma unroll
        for (int q = 0; q < 4; ++q) {
            const int c = c0 + q;
            #pragma unroll
            for (int q2 = 0; q2 < 4; ++q2) {
                if (q2 < q) {
                    const double ljc = __shfl(lreg[q2], c, 32);   // L[c][c0+q2]
                    creg[q] = fma(-lreg[q2], ljc, creg[q]);
                }
            }
            const double dv  = __shfl(creg[q], c, 32);  // C[c][c], fully updated
            const double dcc = sqrt(dv);
            prod *= dv;
            if ((c & 7) == 7) { hld += log(prod); prod = 1.0; }
            const double invd = 1.0 / dcc;
            lreg[q] = (lane == c) ? dcc : creg[q] * invd;
            if (lane == c) C[c][32] = invd;             // stash 1/L[c][c]
        }
        // write finalized panel columns to LDS (L values, as unblocked)
        #pragma unroll
        for (int q = 0; q < 4; ++q) C[lane][c0 + q] = lreg[q];
        if (cb < 7) {
            // next block's 4 columns: update in registers (become creg)
            #pragma unroll
            for (int q = 0; q < 4; ++q) {
                const int c2 = c0 + 4 + q;
                double tmp = C[lane][c2];
                #pragma unroll
                for (int q2 = 0; q2 < 4; ++q2) {
                    const double lc2 = __shfl(lreg[q2], c2, 32);  // L[c2][c0+q2]
                    tmp = fma(-lreg[q2], lc2, tmp);
                }
                creg[q] = tmp;
            }
            // remaining trailing columns: one chained RMW per column
            #pragma unroll
            for (int c2 = 0; c2 < 32; ++c2) {
                if (c2 >= c0 + 8) {
                    double tmp = C[lane][c2];
                    #pragma unroll
                    for (int q2 = 0; q2 < 4; ++q2) {
                        const double lc2 = __shfl(lreg[q2], c2, 32);
                        tmp = fma(-lreg[q2], lc2, tmp);
                    }
                    C[lane][c2] = tmp;
                }
            }
        }
    }
    hld *= 0.5;   // dv = Lcc^2

    // ---- P4 (+fused P5a): forward substitution, lane = column. ----
    // x[] lane-local registers, ALL statically indexed (rule #20): the bf16
    // split + stores happen inside the unrolled loop on the fresh scalar.
    double x[32];
    #pragma unroll
    for (int rr = 0; rr < 32; ++rr) {
        double s = (rr == lane) ? 1.0 : 0.0;
        #pragma unroll
        for (int j = 0; j < rr; ++j)
            s = fma(-C[rr][j], x[j], s);    // C[rr][j] broadcast read
        const double xr = s * C[rr][32];
        x[rr] = xr;
        C[rr][lane] = xr;                   // X row rr (L row rr is dead)

        const float f0 = (float)xr;
        const short h1 = f2bf(f0);
        const float r1 = f0 - bf2f(h1);
        const short h2 = f2bf(r1);
        const float r2 = r1 - bf2f(h2);
        const short h3 = f2bf(r2);
        const size_t base = (size_t)pair * 1024 + (size_t)rr * 32 + lane;
        L1[base] = h1; L2[base] = h2; L3[base] = h3;
    }

    // ---- P5b: b row `lane` = sum_j X[lane][j] * mu[j] (f64, asc j) ----
    // FULL unroll: shuffle index j compile-time -> v_readlane.
    const double mu_l = (double)mean_p[(size_t)pair * 32 + lane];
    double bacc = 0.0;
    #pragma unroll
    for (int j = 0; j < 32; ++j)
        bacc += C[lane][j] * __shfl(mu_l, j, 32);   // C row lane == X row lane
    bOut[(size_t)pair * 32 + lane] = (float)bacc;

    // ---- P5c: c constant (product-butterfly for sum log std, 1 log) ----
    double sprod = (double)ds_stds[dd * 32 + lane];
    #pragma unroll
    for (int off = 16; off >= 1; off >>= 1)
        sprod *= __shfl_xor(sprod, off, 32);
    if (lane == 0) {
        const double lsd = log(sprod);
        const float* mrow = mix + dd * 8;
        double mx = (double)mrow[0];
        #pragma unroll
        for (int q = 1; q < 8; ++q) mx = fmax(mx, (double)mrow[q]);
        double se = 0.0;
        #pragma unroll
        for (int q = 0; q < 8; ++q) se += exp((double)mrow[q] - mx);
        const double logpi = (double)mrow[k] - mx - log(se);
        const double LOG2PI = 1.8378770664093454836;  // log(2*pi)
        cOut[pair] = (float)(logpi - hld - 16.0 * LOG2PI - lsd);
    }
}

// MFMA heavy kernel: verbatim round 13..17 (passing).
__global__ __launch_bounds__(64) void gmm_main(
    const float* __restrict__ data,     // [1024,256,32]
    const float* __restrict__ ds_means, // [256,32]
    const float* __restrict__ ds_stds,  // [256,32]
    const short* __restrict__ L1,       // [2048,32,32] bf16 hi
    const short* __restrict__ L2,       // mid
    const short* __restrict__ L3,       // lo
    const float* __restrict__ bvec,     // [2048,32]
    const float* __restrict__ cdk,      // [2048]
    float* __restrict__ out)            // [1024,256]
{
    const int dd = blockIdx.x;          // 0..255
    const int sc = blockIdx.y;          // 0..15
    const int t  = threadIdx.x;         // 0..63

    __shared__ short y1[4][64][8];      // [j-block][sample][j-in-block]
    __shared__ short y2[4][64][8];
    __shared__ short y3[4][64][8];

    float mn[32], is[32];
    {
        const float4* mp = (const float4*)(ds_means + dd * 32);
        const float4* sp = (const float4*)(ds_stds + dd * 32);
        #pragma unroll
        for (int q = 0; q < 8; ++q) {
            const float4 mv = mp[q];
            const float4 sv = sp[q];
            const int j4 = 4 * q;
            mn[j4+0] = mv.x; mn[j4+1] = mv.y; mn[j4+2] = mv.z; mn[j4+3] = mv.w;
            is[j4+0] = 1.0f / sv.x; is[j4+1] = 1.0f / sv.y;
            is[j4+2] = 1.0f / sv.z; is[j4+3] = 1.0f / sv.w;
        }
    }

    {
        const int s = sc * 64 + t;
        const float4* xp = (const float4*)(data + ((size_t)s * 256 + dd) * 32);
        float y[32];
        #pragma unroll
        for (int q = 0; q < 8; ++q) {
            const float4 v = xp[q];
            const int j4 = 4 * q;
            y[j4+0] = (v.x - mn[j4+0]) * is[j4+0];
            y[j4+1] = (v.y - mn[j4+1]) * is[j4+1];
            y[j4+2] = (v.z - mn[j4+2]) * is[j4+2];
            y[j4+3] = (v.w - mn[j4+3]) * is[j4+3];
        }
        #pragma unroll
        for (int jb = 0; jb < 4; ++jb) {
            short8 v1, v2, v3;
            #pragma unroll
            for (int e = 0; e < 8; ++e) {
                const float f0 = y[jb*8 + e];
                const short h1 = f2bf(f0);
                const float r1 = f0 - bf2f(h1);
                const short h2 = f2bf(r1);
                const float r2 = r1 - bf2f(h2);
                v1[e] = h1; v2[e] = h2; v3[e] = f2bf(r2);
            }
            *(short8*)&y1[jb][t][0] = v1;
            *(short8*)&y2[jb][t][0] = v2;
            *(short8*)&y3[jb][t][0] = v3;
        }
    }
    __syncthreads();

    const int scol = t & 15;            // sample col / A row within tile
    const int g    = t >> 4;            // k-group (j-block) 0..3

    short8 vb1[4], vb2[4], vb3[4];
    #pragma unroll
    for (int st = 0; st < 4; ++st) {
        const int sl = st * 16 + scol;
        vb1[st] = *(const short8*)&y1[g][sl][0];
        vb2[st] = *(const short8*)&y2[g][sl][0];
        vb3[st] = *(const short8*)&y3[g][sl][0];
    }

    float maha[4][8];
    #pragma unroll
    for (int st = 0; st < 4; ++st)
        #pragma unroll
        for (int k = 0; k < 8; ++k) maha[st][k] = 0.0f;

    #pragma unroll
    for (int mt = 0; mt < 16; ++mt) {
        const int k  = mt >> 1;
        const int ib = (mt & 1) * 16;
        const size_t abase = ((size_t)(dd * 8 + k)) * 1024
                           + (size_t)(ib + scol) * 32 + g * 8;
        const short8 a1 = *(const short8*)(L1 + abase);
        const short8 a2 = *(const short8*)(L2 + abase);
        const short8 a3 = *(const short8*)(L3 + abase);
        const float4 bq = *(const float4*)(bvec + (dd * 8 + k) * 32 + ib + g * 4);
        f32x4 cinit;
        cinit[0] = -bq.x; cinit[1] = -bq.y; cinit[2] = -bq.z; cinit[3] = -bq.w;

        f32x4 acc[4];
        #pragma unroll
        for (int st = 0; st < 4; ++st) acc[st] = cinit;

        #pragma unroll
        for (int st = 0; st < 4; ++st) {
            acc[st] = __builtin_amdgcn_mfma_f32_16x16x32_bf16(a1, vb1[st], acc[st], 0, 0, 0);
            acc[st] = __builtin_amdgcn_mfma_f32_16x16x32_bf16(a1, vb2[st], acc[st], 0, 0, 0);
            acc[st] = __builtin_amdgcn_mfma_f32_16x16x32_bf16(a2, vb1[st], acc[st], 0, 0, 0);
            acc[st] = __builtin_amdgcn_mfma_f32_16x16x32_bf16(a2, vb2[st], acc[st], 0, 0, 0);
            acc[st] = __builtin_amdgcn_mfma_f32_16x16x32_bf16(a1, vb3[st], acc[st], 0, 0, 0);
            acc[st] = __builtin_amdgcn_mfma_f32_16x16x32_bf16(a3, vb1[st], acc[st], 0, 0, 0);
        }

        #pragma unroll
        for (int st = 0; st < 4; ++st) {
            float sq = fmaf(acc[st][0], acc[st][0],
                       fmaf(acc[st][1], acc[st][1],
                       fmaf(acc[st][2], acc[st][2], acc[st][3] * acc[st][3])));
            sq += __shfl_xor(sq, 16);
            sq += __shfl_xor(sq, 32);
            maha[st][k] += sq;
        }
    }

    const float* cb = cdk + dd * 8;
    #pragma unroll
    for (int st = 0; st < 4; ++st) {
        float a[8];
        #pragma unroll
        for (int k = 0; k < 8; ++k) a[k] = cb[k] - 0.5f * maha[st][k];
        float m = a[0];
        #pragma unroll
        for (int k = 1; k < 8; ++k) m = fmaxf(m, a[k]);
        float e = 0.0f;
        #pragma unroll
        for (int k = 0; k < 8; ++k) e += expf(a[k] - m);
        if (t < 16) {
            const int s = sc * 64 + st * 16 + scol;
            out[(size_t)s * 256 + dd] = m + logf(e);
        }
    }
}

extern "C" void kernel_launch(void* const* d_in, const int* in_sizes, int n_in,
                              void* d_out, int out_size, void* d_ws, size_t ws_size,
                              hipStream_t stream) {
    const float* data   = (const float*)d_in[0];   // [1024,256,32]
    const float* mix    = (const float*)d_in[1];   // [256,8]
    const float* mean_p = (const float*)d_in[2];   // [256,8,32]
    const float* cov_p  = (const float*)d_in[3];   // [256,8,32,32]
    const float* ds_m   = (const float*)d_in[4];   // [256,32]
    const float* ds_s   = (const float*)d_in[5];   // [256,32]
    float* out = (float*)d_out;

    short* L1 = (short*)d_ws;                   // 2048*1024 bf16
    short* L2 = L1 + 2048 * 1024;
    short* L3 = L2 + 2048 * 1024;
    float* bvec = (float*)(L3 + 2048 * 1024);   // 2048*32 f32
    float* cdk  = bvec + 2048 * 32;             // 2048 f32

    gmm_precompute<<<512, 128, 0, stream>>>(mix, mean_p, cov_p, ds_s,
                                            L1, L2, L3, bvec, cdk);
    dim3 grid(256, 16);
    gmm_main<<<grid, 64, 0, stream>>>(data, ds_m, ds_s, L1, L2, L3,
                                      bvec, cdk, out);
}

// Round 22
// 84.215 us; speedup vs baseline: 2.5760x; 1.0278x over previous
//
#include <hip/hip_runtime.h>
#include <hip/hip_bf16.h>
#include <math.h>

// GMM log-prob, S=1024 D=256 K=8 d=32. Target = dtype-faithful f32 numpy ref.
// cov is replicated BIT-EXACTLY in f32 per numpy's SSE3-baseline einsum
// (mul-round + 4-lane reversed add chains + hadd tree + f32 ridge). Do not
// perturb that ordering -- it is what makes the test pass (absmax 12 < 14.88).
//
// Round 22: split P2 (cov) out of the latency chain. cov entries are fully
// independent -> own kernel at 2048 blocks (2 waves/SIMD + ILP, runs at issue
// rate) writing packed-lower f32 cov (f32 mem round-trip is bit-exact).
// gmm_precompute = r17 verbatim with P2 replaced by a cov load.
// ws: L1|L2|L3 bf16 [2048*1024 ea] | b f32 | c f32 | covt f32 [2048*544+64]
//   total 17.31 MB (<= proven 17.32 MB capacity from rounds 2-4).
// Main kernel verbatim round 13..17 (MFMA, 3-way bf16 split).

typedef __attribute__((ext_vector_type(8))) short short8;
typedef __attribute__((ext_vector_type(4))) float f32x4;

__device__ __forceinline__ short f2bf(float f) {
    __hip_bfloat16 h = __float2bfloat16(f);
    return *reinterpret_cast<short*>(&h);
}
__device__ __forceinline__ float bf2f(short s) {
    __hip_bfloat16 h;
    *reinterpret_cast<short*>(&h) = s;
    return __bfloat162float(h);
}

// Kernel A: cov (f32, exact SSE3-emulated order), packed lower triangle.
// One block per pair; lane owns column c = t&31 (wc hoisted to registers);
// iterates rows r = 2i + (t>>5). Entry (r,c): p[j] = fl(W[r][j]*W[c][j]) --
// identical values to r17's in-line P2 (fl(a*b) == fl(b*a)).
__global__ __launch_bounds__(64) void gmm_cov(
    const float* __restrict__ cov_p,    // [2048,32,32]
    float* __restrict__ covt)           // [2048,544] packed lower
{
    const int pair = blockIdx.x;        // 0..2047
    const int t    = threadIdx.x;       // 0..63

    __shared__ float W[32][33];         // +1 pad: conflict-free row reads
    {
        const float4* wp = (const float4*)(cov_p + (size_t)pair * 1024);
        #pragma unroll
        for (int q = 0; q < 4; ++q) {
            const int e = t + 64 * q;   // 0..255 float4s
            const float4 v = wp[e];
            const int row = e >> 3, col = (e & 7) * 4;
            W[row][col+0] = v.x; W[row][col+1] = v.y;
            W[row][col+2] = v.z; W[row][col+3] = v.w;
        }
    }
    __syncthreads();

    const int c  = t & 31;
    const int hh = t >> 5;

    float wc[32];
    #pragma unroll
    for (int j = 0; j < 32; ++j) wc[j] = W[c][j];

    #pragma unroll
    for (int i = 0; i < 16; ++i) {
        const int r = 2 * i + hh;
        if (c <= r) {
            float p[32];
            #pragma unroll
            for (int j = 0; j < 32; ++j)
                p[j] = __fmul_rn(W[r][j], wc[j]);   // W[r][j]: broadcast read
            float acc[4];
            #pragma unroll
            for (int l = 0; l < 4; ++l) {
                float t1 = p[12+l];
                t1 = __fadd_rn(p[8+l], t1);
                t1 = __fadd_rn(p[4+l], t1);
                t1 = __fadd_rn(p[0+l], t1);
                float t2 = __fadd_rn(p[28+l], t1);
                t2 = __fadd_rn(p[24+l], t2);
                t2 = __fadd_rn(p[20+l], t2);
                acc[l] = __fadd_rn(p[16+l], t2);
            }
            float s = __fadd_rn(__fadd_rn(acc[0], acc[1]),
                                __fadd_rn(acc[2], acc[3]));
            if (c == r) s = __fadd_rn(s, 1.0e-5f);
            covt[(size_t)pair * 544 + (r * (r + 1)) / 2 + c] = s;
        }
    }
}

// Kernel B: r17 verbatim with P2 replaced by packed-cov load (bit-exact).
__global__ __launch_bounds__(128, 1) void gmm_precompute(
    const float* __restrict__ mix,      // [256,8]
    const float* __restrict__ mean_p,   // [256,8,32]
    const float* __restrict__ covt,     // [2048,544] packed lower f32
    const float* __restrict__ ds_stds,  // [256,32]
    short* __restrict__ L1,             // [2048,32,32] bf16 hi
    short* __restrict__ L2,             // [2048,32,32] bf16 mid
    short* __restrict__ L3,             // [2048,32,32] bf16 lo
    float* __restrict__ bOut,           // [2048,32]
    float* __restrict__ cOut)           // [2048]
{
    const int tid  = threadIdx.x;
    const int sub  = tid >> 5;                 // 0..3 half-wave in block
    const int lane = tid & 31;
    const int pair = blockIdx.x * 4 + sub;     // 0..2047
    const int dd   = pair >> 3;
    const int k    = pair & 7;

    __shared__ double Csh[4][32][33];          // [sub][row][col]; col32 = invD
    double (*C)[33] = Csh[sub];

    // ---- P2': load packed lower cov (f32 -> f64, bit-exact) into LDS ----
    // c > lane reads spill into the next rows' entries: garbage, unused by
    // P3 (only lower triangle is consumed); covt has +64 tail padding.
    {
        const float* src = covt + (size_t)pair * 544 + (lane * (lane + 1)) / 2;
        #pragma unroll
        for (int c = 0; c < 32; ++c)
            C[lane][c] = (double)src[c];
    }

    // ---- P3: blocked Cholesky (f64), 4-col panels, lane = row. ----
    // Element-wise FP order identical to the unblocked version.
    double hld = 0.0, prod = 1.0;
    double creg[4], lreg[4];
    #pragma unroll
    for (int q = 0; q < 4; ++q) creg[q] = C[lane][q];

    #pragma unroll
    for (int cb = 0; cb < 8; ++cb) {
        const int c0 = cb * 4;
        // panel: finalize columns c0..c0+3
        #pragma unroll
        for (int q = 0; q < 4; ++q) {
            const int c = c0 + q;
            #pragma unroll
            for (int q2 = 0; q2 < 4; ++q2) {
                if (q2 < q) {
                    const double ljc = __shfl(lreg[q2], c, 32);   // L[c][c0+q2]
                    creg[q] = fma(-lreg[q2], ljc, creg[q]);
                }
            }
            const double dv  = __shfl(creg[q], c, 32);  // C[c][c], fully updated
            const double dcc = sqrt(dv);
            prod *= dv;
            if ((c & 7) == 7) { hld += log(prod); prod = 1.0; }
            const double invd = 1.0 / dcc;
            lreg[q] = (lane == c) ? dcc : creg[q] * invd;
            if (lane == c) C[c][32] = invd;             // stash 1/L[c][c]
        }
        // write finalized panel columns to LDS (L values, as unblocked)
        #pragma unroll
        for (int q = 0; q < 4; ++q) C[lane][c0 + q] = lreg[q];
        if (cb < 7) {
            // next block's 4 columns: update in registers (become creg)
            #pragma unroll
            for (int q = 0; q < 4; ++q) {
                const int c2 = c0 + 4 + q;
                double tmp = C[lane][c2];
                #pragma unroll
                for (int q2 = 0; q2 < 4; ++q2) {
                    const double lc2 = __shfl(lreg[q2], c2, 32);  // L[c2][c0+q2]
                    tmp = fma(-lreg[q2], lc2, tmp);
                }
                creg[q] = tmp;
            }
            // remaining trailing columns: one chained RMW per column
            #pragma unroll
            for (int c2 = 0; c2 < 32; ++c2) {
                if (c2 >= c0 + 8) {
                    double tmp = C[lane][c2];
                    #pragma unroll
                    for (int q2 = 0; q2 < 4; ++q2) {
                        const double lc2 = __shfl(lreg[q2], c2, 32);
                        tmp = fma(-lreg[q2], lc2, tmp);
                    }
                    C[lane][c2] = tmp;
                }
            }
        }
    }
    hld *= 0.5;   // dv = Lcc^2

    // ---- P4 (+fused P5a): forward substitution, lane = column. ----
    // x[] lane-local registers, ALL statically indexed (rule #20): the bf16
    // split + stores happen inside the unrolled loop on the fresh scalar.
    double x[32];
    #pragma unroll
    for (int rr = 0; rr < 32; ++rr) {
        double s = (rr == lane) ? 1.0 : 0.0;
        #pragma unroll
        for (int j = 0; j < rr; ++j)
            s = fma(-C[rr][j], x[j], s);    // C[rr][j] broadcast read
        const double xr = s * C[rr][32];
        x[rr] = xr;
        C[rr][lane] = xr;                   // X row rr (L row rr is dead)

        const float f0 = (float)xr;
        const short h1 = f2bf(f0);
        const float r1 = f0 - bf2f(h1);
        const short h2 = f2bf(r1);
        const float r2 = r1 - bf2f(h2);
        const short h3 = f2bf(r2);
        const size_t base = (size_t)pair * 1024 + (size_t)rr * 32 + lane;
        L1[base] = h1; L2[base] = h2; L3[base] = h3;
    }

    // ---- P5b: b row `lane` = sum_j X[lane][j] * mu[j] (f64, asc j) ----
    const double mu_l = (double)mean_p[(size_t)pair * 32 + lane];
    double bacc = 0.0;
    #pragma unroll
    for (int j = 0; j < 32; ++j)
        bacc += C[lane][j] * __shfl(mu_l, j, 32);   // C row lane == X row lane
    bOut[(size_t)pair * 32 + lane] = (float)bacc;

    // ---- P5c: c constant (product-butterfly for sum log std, 1 log) ----
    double sprod = (double)ds_stds[dd * 32 + lane];
    #pragma unroll
    for (int off = 16; off >= 1; off >>= 1)
        sprod *= __shfl_xor(sprod, off, 32);
    if (lane == 0) {
        const double lsd = log(sprod);
        const float* mrow = mix + dd * 8;
        double mx = (double)mrow[0];
        #pragma unroll
        for (int q = 1; q < 8; ++q) mx = fmax(mx, (double)mrow[q]);
        double se = 0.0;
        #pragma unroll
        for (int q = 0; q < 8; ++q) se += exp((double)mrow[q] - mx);
        const double logpi = (double)mrow[k] - mx - log(se);
        const double LOG2PI = 1.8378770664093454836;  // log(2*pi)
        cOut[pair] = (float)(logpi - hld - 16.0 * LOG2PI - lsd);
    }
}

// MFMA heavy kernel: verbatim round 13..17 (passing).
__global__ __launch_bounds__(64) void gmm_main(
    const float* __restrict__ data,     // [1024,256,32]
    const float* __restrict__ ds_means, // [256,32]
    const float* __restrict__ ds_stds,  // [256,32]
    const short* __restrict__ L1,       // [2048,32,32] bf16 hi
    const short* __restrict__ L2,       // mid
    const short* __restrict__ L3,       // lo
    const float* __restrict__ bvec,     // [2048,32]
    const float* __restrict__ cdk,      // [2048]
    float* __restrict__ out)            // [1024,256]
{
    const int dd = blockIdx.x;          // 0..255
    const int sc = blockIdx.y;          // 0..15
    const int t  = threadIdx.x;         // 0..63

    __shared__ short y1[4][64][8];      // [j-block][sample][j-in-block]
    __shared__ short y2[4][64][8];
    __shared__ short y3[4][64][8];

    float mn[32], is[32];
    {
        const float4* mp = (const float4*)(ds_means + dd * 32);
        const float4* sp = (const float4*)(ds_stds + dd * 32);
        #pragma unroll
        for (int q = 0; q < 8; ++q) {
            const float4 mv = mp[q];
            const float4 sv = sp[q];
            const int j4 = 4 * q;
            mn[j4+0] = mv.x; mn[j4+1] = mv.y; mn[j4+2] = mv.z; mn[j4+3] = mv.w;
            is[j4+0] = 1.0f / sv.x; is[j4+1] = 1.0f / sv.y;
            is[j4+2] = 1.0f / sv.z; is[j4+3] = 1.0f / sv.w;
        }
    }

    {
        const int s = sc * 64 + t;
        const float4* xp = (const float4*)(data + ((size_t)s * 256 + dd) * 32);
        float y[32];
        #pragma unroll
        for (int q = 0; q < 8; ++q) {
            const float4 v = xp[q];
            const int j4 = 4 * q;
            y[j4+0] = (v.x - mn[j4+0]) * is[j4+0];
            y[j4+1] = (v.y - mn[j4+1]) * is[j4+1];
            y[j4+2] = (v.z - mn[j4+2]) * is[j4+2];
            y[j4+3] = (v.w - mn[j4+3]) * is[j4+3];
        }
        #pragma unroll
        for (int jb = 0; jb < 4; ++jb) {
            short8 v1, v2, v3;
            #pragma unroll
            for (int e = 0; e < 8; ++e) {
                const float f0 = y[jb*8 + e];
                const short h1 = f2bf(f0);
                const float r1 = f0 - bf2f(h1);
                const short h2 = f2bf(r1);
                const float r2 = r1 - bf2f(h2);
                v1[e] = h1; v2[e] = h2; v3[e] = f2bf(r2);
            }
            *(short8*)&y1[jb][t][0] = v1;
            *(short8*)&y2[jb][t][0] = v2;
            *(short8*)&y3[jb][t][0] = v3;
        }
    }
    __syncthreads();

    const int scol = t & 15;            // sample col / A row within tile
    const int g    = t >> 4;            // k-group (j-block) 0..3

    short8 vb1[4], vb2[4], vb3[4];
    #pragma unroll
    for (int st = 0; st < 4; ++st) {
        const int sl = st * 16 + scol;
        vb1[st] = *(const short8*)&y1[g][sl][0];
        vb2[st] = *(const short8*)&y2[g][sl][0];
        vb3[st] = *(const short8*)&y3[g][sl][0];
    }

    float maha[4][8];
    #pragma unroll
    for (int st = 0; st < 4; ++st)
        #pragma unroll
        for (int k = 0; k < 8; ++k) maha[st][k] = 0.0f;

    #pragma unroll
    for (int mt = 0; mt < 16; ++mt) {
        const int k  = mt >> 1;
        const int ib = (mt & 1) * 16;
        const size_t abase = ((size_t)(dd * 8 + k)) * 1024
                           + (size_t)(ib + scol) * 32 + g * 8;
        const short8 a1 = *(const short8*)(L1 + abase);
        const short8 a2 = *(const short8*)(L2 + abase);
        const short8 a3 = *(const short8*)(L3 + abase);
        const float4 bq = *(const float4*)(bvec + (dd * 8 + k) * 32 + ib + g * 4);
        f32x4 cinit;
        cinit[0] = -bq.x; cinit[1] = -bq.y; cinit[2] = -bq.z; cinit[3] = -bq.w;

        f32x4 acc[4];
        #pragma unroll
        for (int st = 0; st < 4; ++st) acc[st] = cinit;

        #pragma unroll
        for (int st = 0; st < 4; ++st) {
            acc[st] = __builtin_amdgcn_mfma_f32_16x16x32_bf16(a1, vb1[st], acc[st], 0, 0, 0);
            acc[st] = __builtin_amdgcn_mfma_f32_16x16x32_bf16(a1, vb2[st], acc[st], 0, 0, 0);
            acc[st] = __builtin_amdgcn_mfma_f32_16x16x32_bf16(a2, vb1[st], acc[st], 0, 0, 0);
            acc[st] = __builtin_amdgcn_mfma_f32_16x16x32_bf16(a2, vb2[st], acc[st], 0, 0, 0);
            acc[st] = __builtin_amdgcn_mfma_f32_16x16x32_bf16(a1, vb3[st], acc[st], 0, 0, 0);
            acc[st] = __builtin_amdgcn_mfma_f32_16x16x32_bf16(a3, vb1[st], acc[st], 0, 0, 0);
        }

        #pragma unroll
        for (int st = 0; st < 4; ++st) {
            float sq = fmaf(acc[st][0], acc[st][0],
                       fmaf(acc[st][1], acc[st][1],
                       fmaf(acc[st][2], acc[st][2], acc[st][3] * acc[st][3])));
            sq += __shfl_xor(sq, 16);
            sq += __shfl_xor(sq, 32);
            maha[st][k] += sq;
        }
    }

    const float* cb = cdk + dd * 8;
    #pragma unroll
    for (int st = 0; st < 4; ++st) {
        float a[8];
        #pragma unroll
        for (int k = 0; k < 8; ++k) a[k] = cb[k] - 0.5f * maha[st][k];
        float m = a[0];
        #pragma unroll
        for (int k = 1; k < 8; ++k) m = fmaxf(m, a[k]);
        float e = 0.0f;
        #pragma unroll
        for (int k = 0; k < 8; ++k) e += expf(a[k] - m);
        if (t < 16) {
            const int s = sc * 64 + st * 16 + scol;
            out[(size_t)s * 256 + dd] = m + logf(e);
        }
    }
}

extern "C" void kernel_launch(void* const* d_in, const int* in_sizes, int n_in,
                              void* d_out, int out_size, void* d_ws, size_t ws_size,
                              hipStream_t stream) {
    const float* data   = (const float*)d_in[0];   // [1024,256,32]
    const float* mix    = (const float*)d_in[1];   // [256,8]
    const float* mean_p = (const float*)d_in[2];   // [256,8,32]
    const float* cov_p  = (const float*)d_in[3];   // [256,8,32,32]
    const float* ds_m   = (const float*)d_in[4];   // [256,32]
    const float* ds_s   = (const float*)d_in[5];   // [256,32]
    float* out = (float*)d_out;

    short* L1 = (short*)d_ws;                   // 2048*1024 bf16
    short* L2 = L1 + 2048 * 1024;
    short* L3 = L2 + 2048 * 1024;
    float* bvec = (float*)(L3 + 2048 * 1024);   // 2048*32 f32
    float* cdk  = bvec + 2048 * 32;             // 2048 f32
    float* covt = cdk + 2048;                   // 2048*544 + 64 f32

    gmm_cov<<<2048, 64, 0, stream>>>(cov_p, covt);
    gmm_precompute<<<512, 128, 0, stream>>>(mix, mean_p, covt, ds_s,
                                            L1, L2, L3, bvec, cdk);
    dim3 grid(256, 16);
    gmm_main<<<grid, 64, 0, stream>>>(data, ds_m, ds_s, L1, L2, L3,
                                      bvec, cdk, out);
}